// Round 1
// baseline (632.369 us; speedup 1.0000x reference)
//
#include <hip/hip_runtime.h>
#include <stdint.h>

#define B_ 2
#define T_ 2048
#define HID_ 2048
#define H_ 16
#define KVH_ 4
#define D_ 128

typedef __attribute__((ext_vector_type(8))) short short8;
typedef __attribute__((ext_vector_type(4))) float f32x4;

__device__ __forceinline__ uint16_t f2bf(float x) {
  union { float f; uint32_t u; } c; c.f = x;
  uint32_t r = c.u + 0x7fffu + ((c.u >> 16) & 1u);
  return (uint16_t)(r >> 16);
}
__device__ __forceinline__ float bf2f(uint16_t b) {
  union { uint32_t u; float f; } c; c.u = ((uint32_t)b) << 16;
  return c.f;
}

// ---------------- fp32 -> bf16 convert ----------------
__global__ __launch_bounds__(256) void cvt_f32_bf16(const float* __restrict__ in,
                                                    uint16_t* __restrict__ out, int n) {
  int i = (blockIdx.x * 256 + threadIdx.x) * 4;
  if (i >= n) return;
  const float4 v = *reinterpret_cast<const float4*>(in + i);
  union { uint16_t s[4]; uint2 u; } pk;
  pk.s[0] = f2bf(v.x); pk.s[1] = f2bf(v.y); pk.s[2] = f2bf(v.z); pk.s[3] = f2bf(v.w);
  *reinterpret_cast<uint2*>(out + i) = pk.u;
}

__global__ __launch_bounds__(256) void concat_bias(const float* __restrict__ bq,
                                                   const float* __restrict__ bk,
                                                   const float* __restrict__ bv,
                                                   float* __restrict__ out) {
  int i = blockIdx.x * 256 + threadIdx.x;
  if (i < 2048) out[i] = bq[i];
  else if (i < 2560) out[i] = bk[i - 2048];
  else if (i < 3072) out[i] = bv[i - 2560];
}

// ---------------- bt-GEMM: A[M][K] bf16, Bt[N][K] bf16 -> C[M][N] ----------------
#define BM 128
#define BN 128
#define BK 64

template<bool OUT_F32, bool HAS_BIAS>
__global__ __launch_bounds__(256) void gemm_bt(const uint16_t* __restrict__ A,
                                               const uint16_t* __restrict__ Bt,
                                               void* __restrict__ Cv,
                                               const float* __restrict__ bias,
                                               int M, int N, int K) {
  __shared__ __align__(16) uint16_t Al[BM * BK];
  __shared__ __align__(16) uint16_t Bl[BN * BK];
  const int tid = threadIdx.x;
  const int w = tid >> 6;
  const int lane = tid & 63;
  const int wr = w >> 1, wc = w & 1;
  const int bm = blockIdx.y * BM;
  const int bn = blockIdx.x * BN;
  const int lm = lane & 15, lg = lane >> 4;
  const int srow = lane >> 3, scol = (lane & 7) * 8;

  f32x4 acc[4][4];
  const f32x4 z4 = {0.f, 0.f, 0.f, 0.f};
#pragma unroll
  for (int i = 0; i < 4; ++i)
#pragma unroll
    for (int j = 0; j < 4; ++j) acc[i][j] = z4;

  for (int k0 = 0; k0 < K; k0 += BK) {
#pragma unroll
    for (int i = 0; i < 4; ++i) {
      const int c = i * 4 + w;
      const int row = c * 8 + srow;
      const uint16_t* gA = A + (size_t)(bm + row) * K + k0 + scol;
      const uint16_t* gB = Bt + (size_t)(bn + row) * K + k0 + scol;
      __builtin_amdgcn_global_load_lds((const __attribute__((address_space(1))) unsigned int*)gA,
                                       (__attribute__((address_space(3))) unsigned int*)(Al + c * 512),
                                       16, 0, 0);
      __builtin_amdgcn_global_load_lds((const __attribute__((address_space(1))) unsigned int*)gB,
                                       (__attribute__((address_space(3))) unsigned int*)(Bl + c * 512),
                                       16, 0, 0);
    }
    __syncthreads();
#pragma unroll
    for (int kk = 0; kk < 2; ++kk) {
      const int ko = kk * 32 + lg * 8;
      short8 af[4], bfr[4];
#pragma unroll
      for (int mi = 0; mi < 4; ++mi)
        af[mi] = *reinterpret_cast<const short8*>(Al + (wr * 64 + mi * 16 + lm) * BK + ko);
#pragma unroll
      for (int ni = 0; ni < 4; ++ni)
        bfr[ni] = *reinterpret_cast<const short8*>(Bl + (wc * 64 + ni * 16 + lm) * BK + ko);
#pragma unroll
      for (int mi = 0; mi < 4; ++mi)
#pragma unroll
        for (int ni = 0; ni < 4; ++ni)
          acc[mi][ni] = __builtin_amdgcn_mfma_f32_16x16x32_bf16(af[mi], bfr[ni], acc[mi][ni], 0, 0, 0);
    }
    __syncthreads();
  }

#pragma unroll
  for (int mi = 0; mi < 4; ++mi) {
#pragma unroll
    for (int ni = 0; ni < 4; ++ni) {
      const int col = bn + wc * 64 + ni * 16 + lm;
      float bb = 0.f;
      if (HAS_BIAS) bb = bias[col];
#pragma unroll
      for (int r = 0; r < 4; ++r) {
        const int row = bm + wr * 64 + mi * 16 + lg * 4 + r;
        const float v = acc[mi][ni][r] + bb;
        if (OUT_F32) reinterpret_cast<float*>(Cv)[(size_t)row * N + col] = v;
        else reinterpret_cast<uint16_t*>(Cv)[(size_t)row * N + col] = f2bf(v);
      }
    }
  }
}

// ---------------- RoPE + scatter to per-head layouts ----------------
__global__ __launch_bounds__(256) void rope_scatter(const uint16_t* __restrict__ raw,
                                                    const float* __restrict__ cosp,
                                                    const float* __restrict__ sinp,
                                                    uint16_t* __restrict__ Qo,
                                                    uint16_t* __restrict__ Ko,
                                                    uint16_t* __restrict__ Vo) {
  const int c = blockIdx.x * 256 + threadIdx.x;  // 0..3071
  const int m = blockIdx.y;                      // 0..4095
  const int b = m >> 11, tt = m & 2047;
  float x = bf2f(raw[(size_t)m * 3072 + c]);
  if (c < 2560) {
    const int d = c & 127;
    const int pc = c ^ 64;
    const float px = bf2f(raw[(size_t)m * 3072 + pc]);
    const float cs = cosp[((size_t)b * T_ + tt) * D_ + d];
    const float sn = sinp[((size_t)b * T_ + tt) * D_ + d];
    x = x * cs + (d < 64 ? -px : px) * sn;
  }
  if (c < 2048) {
    const int hh = c >> 7, d = c & 127;
    Qo[(((size_t)(b * H_ + hh)) * T_ + tt) * D_ + d] = f2bf(x);
  } else if (c < 2560) {
    const int hh = (c - 2048) >> 7, d = c & 127;
    Ko[(((size_t)(b * KVH_ + hh)) * T_ + tt) * D_ + d] = f2bf(x);
  } else {
    const int hh = (c - 2560) >> 7, d = c & 127;
    Vo[(((size_t)(b * KVH_ + hh)) * T_ + tt) * D_ + d] = f2bf(x);
  }
}

// ---------------- causal GQA flash attention ----------------
#define KVBLK 32
#define KPAD 136
#define VPAD 40
#define PPAD 40

__global__ __launch_bounds__(256) void attn_fwd(const uint16_t* __restrict__ Qb,
                                                const uint16_t* __restrict__ Kb,
                                                const uint16_t* __restrict__ Vb,
                                                uint16_t* __restrict__ Ab) {
  __shared__ __align__(16) uint16_t Kl[KVBLK * KPAD];
  __shared__ __align__(16) uint16_t Vt[D_ * VPAD];
  __shared__ __align__(16) uint16_t Pl[4 * 16 * PPAD];
  const int tid = threadIdx.x;
  const int w = tid >> 6, lane = tid & 63;
  const int lm = lane & 15, lg = lane >> 4;
  const int bh = blockIdx.y;
  const int b = bh >> 4, h = bh & 15;
  const int kvh = h >> 2;
  const int qt = blockIdx.x;
  const int q0 = qt * 64;

  // Q fragments for this wave's 16 rows (A-frag layout: m=lane&15, k=(lane>>4)*8+j)
  const uint16_t* Qw = Qb + (((size_t)(b * H_ + h)) * T_ + q0 + w * 16) * D_;
  short8 qf[4];
#pragma unroll
  for (int kk = 0; kk < 4; ++kk)
    qf[kk] = *reinterpret_cast<const short8*>(Qw + (size_t)lm * D_ + kk * 32 + lg * 8);

  f32x4 o[8];
  const f32x4 z4 = {0.f, 0.f, 0.f, 0.f};
#pragma unroll
  for (int f = 0; f < 8; ++f) o[f] = z4;
  float mrow[4] = {-1e30f, -1e30f, -1e30f, -1e30f};
  float lrow[4] = {0.f, 0.f, 0.f, 0.f};

  const float sc = 0.08838834764831845f * 1.44269504088896341f;  // 1/sqrt(128) * log2e

  const uint16_t* Kbase = Kb + ((size_t)(b * KVH_ + kvh)) * T_ * D_;
  const uint16_t* Vbase = Vb + ((size_t)(b * KVH_ + kvh)) * T_ * D_;

  const int nkv = 2 * qt + 2;
  for (int t = 0; t < nkv; ++t) {
    const int kv0 = t * KVBLK;
    __syncthreads();  // prior PV reads of Kl/Vt done before restage
#pragma unroll
    for (int rr = 0; rr < 2; ++rr) {
      const int flat = (rr * 256 + tid) * 8;
      const int row = flat >> 7, col = flat & 127;
      short8 kv = *reinterpret_cast<const short8*>(Kbase + ((size_t)(kv0 + row)) * D_ + col);
      *reinterpret_cast<short8*>(Kl + row * KPAD + col) = kv;
      short8 vv = *reinterpret_cast<const short8*>(Vbase + ((size_t)(kv0 + row)) * D_ + col);
#pragma unroll
      for (int j = 0; j < 8; ++j)
        Vt[(col + j) * VPAD + row] = (uint16_t)vv[j];
    }
    __syncthreads();

    // S = Q K^T (bt pattern: B-frag col = kv row of K)
    f32x4 s[2];
    s[0] = z4; s[1] = z4;
#pragma unroll
    for (int nf = 0; nf < 2; ++nf)
#pragma unroll
      for (int kk = 0; kk < 4; ++kk) {
        short8 kf = *reinterpret_cast<const short8*>(Kl + (nf * 16 + lm) * KPAD + kk * 32 + lg * 8);
        s[nf] = __builtin_amdgcn_mfma_f32_16x16x32_bf16(qf[kk], kf, s[nf], 0, 0, 0);
      }

    const int rowg = q0 + w * 16 + lg * 4;
    float sv[2][4], rmax[4] = {-1e30f, -1e30f, -1e30f, -1e30f};
#pragma unroll
    for (int nf = 0; nf < 2; ++nf) {
      const int colg = kv0 + nf * 16 + lm;
#pragma unroll
      for (int r = 0; r < 4; ++r) {
        float v = s[nf][r] * sc;
        if (colg > rowg + r) v = -1e30f;  // causal mask (log2 domain)
        sv[nf][r] = v;
        rmax[r] = fmaxf(rmax[r], v);
      }
    }
#pragma unroll
    for (int r = 0; r < 4; ++r) {
      float v = rmax[r];
      v = fmaxf(v, __shfl_xor(v, 1));
      v = fmaxf(v, __shfl_xor(v, 2));
      v = fmaxf(v, __shfl_xor(v, 4));
      v = fmaxf(v, __shfl_xor(v, 8));
      rmax[r] = fmaxf(mrow[r], v);  // new running max
    }
    float alpha[4];
#pragma unroll
    for (int r = 0; r < 4; ++r) {
      alpha[r] = exp2f(mrow[r] - rmax[r]);
      mrow[r] = rmax[r];
    }
    float rsum[4] = {0.f, 0.f, 0.f, 0.f};
    uint16_t pb[2][4];
#pragma unroll
    for (int nf = 0; nf < 2; ++nf)
#pragma unroll
      for (int r = 0; r < 4; ++r) {
        const float p = exp2f(sv[nf][r] - mrow[r]);
        rsum[r] += p;
        pb[nf][r] = f2bf(p);
      }
#pragma unroll
    for (int r = 0; r < 4; ++r) {
      float v = rsum[r];
      v += __shfl_xor(v, 1);
      v += __shfl_xor(v, 2);
      v += __shfl_xor(v, 4);
      v += __shfl_xor(v, 8);
      lrow[r] = lrow[r] * alpha[r] + v;
    }
#pragma unroll
    for (int f = 0; f < 8; ++f)
#pragma unroll
      for (int r = 0; r < 4; ++r)
        o[f][r] *= alpha[r];

    // P -> LDS (C/D layout) then re-read as A-frag
    uint16_t* Pw = Pl + w * 16 * PPAD;
#pragma unroll
    for (int nf = 0; nf < 2; ++nf)
#pragma unroll
      for (int r = 0; r < 4; ++r)
        Pw[(lg * 4 + r) * PPAD + nf * 16 + lm] = pb[nf][r];
    __syncthreads();  // drain ds_writes (and uniform barrier count)
    const short8 pf = *reinterpret_cast<const short8*>(Pw + lm * PPAD + lg * 8);
#pragma unroll
    for (int f = 0; f < 8; ++f) {
      short8 vf = *reinterpret_cast<const short8*>(Vt + (f * 16 + lm) * VPAD + lg * 8);
      o[f] = __builtin_amdgcn_mfma_f32_16x16x32_bf16(pf, vf, o[f], 0, 0, 0);
    }
  }

#pragma unroll
  for (int f = 0; f < 8; ++f) {
    const int col = h * D_ + f * 16 + lm;
#pragma unroll
    for (int r = 0; r < 4; ++r) {
      const int trow = q0 + w * 16 + lg * 4 + r;
      const float v = o[f][r] / lrow[r];
      Ab[((size_t)(b * T_ + trow)) * (H_ * D_) + col] = f2bf(v);
    }
  }
}

// ---------------- launch ----------------
extern "C" void kernel_launch(void* const* d_in, const int* in_sizes, int n_in,
                              void* d_out, int out_size, void* d_ws, size_t ws_size,
                              hipStream_t stream) {
  const float* hidden = (const float*)d_in[0];
  const float* cosp   = (const float*)d_in[1];
  const float* sinp   = (const float*)d_in[2];
  // d_in[3] = attention_mask: exactly causal, implemented in-kernel
  const float* Wq = (const float*)d_in[4];
  const float* bq = (const float*)d_in[5];
  const float* Wk = (const float*)d_in[6];
  const float* bk = (const float*)d_in[7];
  const float* Wv = (const float*)d_in[8];
  const float* bv = (const float*)d_in[9];
  const float* Wo = (const float*)d_in[10];

  char* ws = (char*)d_ws;
  uint16_t* hidb   = (uint16_t*)(ws);              // 4096x2048 bf16   16,777,216 B
  uint16_t* wqkv   = (uint16_t*)(ws + 16777216);   // 3072x2048 bf16   12,582,912 B
  uint16_t* wob    = (uint16_t*)(ws + 29360128);   // 2048x2048 bf16    8,388,608 B
  float*    biasq  = (float*)   (ws + 37748736);   // 3072 f32             12,288 B
  uint16_t* qkvraw = (uint16_t*)(ws + 37761024);   // 4096x3072 bf16   25,165,824 B
  uint16_t* Qb     = (uint16_t*)(ws + 62926848);   // [2][16][2048][128] 16,777,216 B
  uint16_t* Kb     = (uint16_t*)(ws + 79704064);   // [2][4][2048][128]   4,194,304 B
  uint16_t* Vb     = (uint16_t*)(ws + 83898368);   // [2][4][2048][128]   4,194,304 B
  uint16_t* Ab     = (uint16_t*)(ws + 88092672);   // [2][2048][2048]   16,777,216 B

  cvt_f32_bf16<<<8192, 256, 0, stream>>>(hidden, hidb, 8388608);
  cvt_f32_bf16<<<4096, 256, 0, stream>>>(Wq, wqkv, 4194304);
  cvt_f32_bf16<<<1024, 256, 0, stream>>>(Wk, wqkv + 4194304, 1048576);
  cvt_f32_bf16<<<1024, 256, 0, stream>>>(Wv, wqkv + 5242880, 1048576);
  cvt_f32_bf16<<<4096, 256, 0, stream>>>(Wo, wob, 4194304);
  concat_bias<<<12, 256, 0, stream>>>(bq, bk, bv, biasq);

  // QKV projection: [4096,2048] x [3072,2048]^T -> [4096,3072] (+bias)
  gemm_bt<false, true><<<dim3(24, 32), 256, 0, stream>>>(hidb, wqkv, qkvraw, biasq, 4096, 3072, 2048);
  // RoPE + scatter
  rope_scatter<<<dim3(12, 4096), 256, 0, stream>>>(qkvraw, cosp, sinp, Qb, Kb, Vb);
  // causal GQA flash attention -> Ab [b][t][h*128+d] bf16
  attn_fwd<<<dim3(32, 32), 256, 0, stream>>>(Qb, Kb, Vb, Ab);
  // output projection: [4096,2048] x [2048,2048]^T -> d_out fp32
  gemm_bt<true, false><<<dim3(16, 32), 256, 0, stream>>>(Ab, wob, d_out, nullptr, 4096, 2048, 2048);
}

// Round 4
// 313.468 us; speedup vs baseline: 2.0173x; 2.0173x over previous
//
#include <hip/hip_runtime.h>
#include <stdint.h>

#define B_ 2
#define T_ 2048
#define HID_ 2048
#define H_ 16
#define KVH_ 4
#define D_ 128

typedef __attribute__((ext_vector_type(8))) short short8;
typedef __attribute__((ext_vector_type(4))) float f32x4;

__device__ __forceinline__ uint16_t f2bf(float x) {
  union { float f; uint32_t u; } c; c.f = x;
  uint32_t r = c.u + 0x7fffu + ((c.u >> 16) & 1u);
  return (uint16_t)(r >> 16);
}
__device__ __forceinline__ float bf2f(uint16_t b) {
  union { uint32_t u; float f; } c; c.u = ((uint32_t)b) << 16;
  return c.f;
}

// ---------------- fp32 -> bf16 convert ----------------
__global__ __launch_bounds__(256) void cvt_f32_bf16(const float* __restrict__ in,
                                                    uint16_t* __restrict__ out, int n) {
  int i = (blockIdx.x * 256 + threadIdx.x) * 4;
  if (i >= n) return;
  const float4 v = *reinterpret_cast<const float4*>(in + i);
  union { uint16_t s[4]; uint2 u; } pk;
  pk.s[0] = f2bf(v.x); pk.s[1] = f2bf(v.y); pk.s[2] = f2bf(v.z); pk.s[3] = f2bf(v.w);
  *reinterpret_cast<uint2*>(out + i) = pk.u;
}

__global__ __launch_bounds__(256) void concat_bias(const float* __restrict__ bq,
                                                   const float* __restrict__ bk,
                                                   const float* __restrict__ bv,
                                                   float* __restrict__ out) {
  int i = blockIdx.x * 256 + threadIdx.x;
  if (i < 2048) out[i] = bq[i];
  else if (i < 2560) out[i] = bk[i - 2048];
  else if (i < 3072) out[i] = bv[i - 2560];
}

// ---------------- bt-GEMM: A[M][K] bf16, Bt[N][K] bf16 -> C[M][N] ----------------
#define BM 128
#define BN 128
#define BK 64

template<bool OUT_F32, bool HAS_BIAS>
__global__ __launch_bounds__(256) void gemm_bt(const uint16_t* __restrict__ A,
                                               const uint16_t* __restrict__ Bt,
                                               void* __restrict__ Cv,
                                               const float* __restrict__ bias,
                                               int M, int N, int K) {
  __shared__ __align__(16) uint16_t Al[BM * BK];
  __shared__ __align__(16) uint16_t Bl[BN * BK];
  const int tid = threadIdx.x;
  const int w = tid >> 6;
  const int lane = tid & 63;
  const int wr = w >> 1, wc = w & 1;
  const int bm = blockIdx.y * BM;
  const int bn = blockIdx.x * BN;
  const int lm = lane & 15, lg = lane >> 4;
  const int srow = lane >> 3, scol = (lane & 7) * 8;

  f32x4 acc[4][4];
  const f32x4 z4 = {0.f, 0.f, 0.f, 0.f};
#pragma unroll
  for (int i = 0; i < 4; ++i)
#pragma unroll
    for (int j = 0; j < 4; ++j) acc[i][j] = z4;

  for (int k0 = 0; k0 < K; k0 += BK) {
#pragma unroll
    for (int i = 0; i < 4; ++i) {
      const int c = i * 4 + w;
      const int row = c * 8 + srow;
      const uint16_t* gA = A + (size_t)(bm + row) * K + k0 + scol;
      const uint16_t* gB = Bt + (size_t)(bn + row) * K + k0 + scol;
      __builtin_amdgcn_global_load_lds((const __attribute__((address_space(1))) unsigned int*)gA,
                                       (__attribute__((address_space(3))) unsigned int*)(Al + c * 512),
                                       16, 0, 0);
      __builtin_amdgcn_global_load_lds((const __attribute__((address_space(1))) unsigned int*)gB,
                                       (__attribute__((address_space(3))) unsigned int*)(Bl + c * 512),
                                       16, 0, 0);
    }
    __syncthreads();
#pragma unroll
    for (int kk = 0; kk < 2; ++kk) {
      const int ko = kk * 32 + lg * 8;
      short8 af[4], bfr[4];
#pragma unroll
      for (int mi = 0; mi < 4; ++mi)
        af[mi] = *reinterpret_cast<const short8*>(Al + (wr * 64 + mi * 16 + lm) * BK + ko);
#pragma unroll
      for (int ni = 0; ni < 4; ++ni)
        bfr[ni] = *reinterpret_cast<const short8*>(Bl + (wc * 64 + ni * 16 + lm) * BK + ko);
#pragma unroll
      for (int mi = 0; mi < 4; ++mi)
#pragma unroll
        for (int ni = 0; ni < 4; ++ni)
          acc[mi][ni] = __builtin_amdgcn_mfma_f32_16x16x32_bf16(af[mi], bfr[ni], acc[mi][ni], 0, 0, 0);
    }
    __syncthreads();
  }

#pragma unroll
  for (int mi = 0; mi < 4; ++mi) {
#pragma unroll
    for (int ni = 0; ni < 4; ++ni) {
      const int col = bn + wc * 64 + ni * 16 + lm;
      float bb = 0.f;
      if (HAS_BIAS) bb = bias[col];
#pragma unroll
      for (int r = 0; r < 4; ++r) {
        const int row = bm + wr * 64 + mi * 16 + lg * 4 + r;
        const float v = acc[mi][ni][r] + bb;
        if (OUT_F32) reinterpret_cast<float*>(Cv)[(size_t)row * N + col] = v;
        else reinterpret_cast<uint16_t*>(Cv)[(size_t)row * N + col] = f2bf(v);
      }
    }
  }
}

// ---------------- RoPE + scatter (Q,K only; V handled by transpose_v) ----------------
__global__ __launch_bounds__(256) void rope_scatter(const uint16_t* __restrict__ raw,
                                                    const float* __restrict__ cosp,
                                                    const float* __restrict__ sinp,
                                                    uint16_t* __restrict__ Qo,
                                                    uint16_t* __restrict__ Ko) {
  const int c = blockIdx.x * 256 + threadIdx.x;  // 0..2559
  const int m = blockIdx.y;                      // 0..4095
  const int b = m >> 11, tt = m & 2047;
  const int d = c & 127;
  const int pc = c ^ 64;
  float x = bf2f(raw[(size_t)m * 3072 + c]);
  const float px = bf2f(raw[(size_t)m * 3072 + pc]);
  const float cs = cosp[((size_t)b * T_ + tt) * D_ + d];
  const float sn = sinp[((size_t)b * T_ + tt) * D_ + d];
  x = x * cs + (d < 64 ? -px : px) * sn;
  if (c < 2048) {
    const int hh = c >> 7;
    Qo[(((size_t)(b * H_ + hh)) * T_ + tt) * D_ + d] = f2bf(x);
  } else {
    const int hh = (c - 2048) >> 7;
    Ko[(((size_t)(b * KVH_ + hh)) * T_ + tt) * D_ + d] = f2bf(x);
  }
}

// ---------------- V transpose: qkvraw cols 2560..3071 -> VtG[b][kvh][d][t] ----------------
__global__ __launch_bounds__(256) void transpose_v(const uint16_t* __restrict__ raw,
                                                   uint16_t* __restrict__ VtG) {
  const int hb = blockIdx.y;            // b*4+kvh, 0..7
  const int b = hb >> 2, kvh = hb & 3;
  const int d = threadIdx.x & 127;
  const int tw = threadIdx.x >> 7;      // 0..1
  const int t0 = blockIdx.x * 16 + tw * 8;
  const uint16_t* src = raw + ((size_t)(b * T_ + t0)) * 3072 + 2560 + kvh * 128 + d;
  union { uint16_t s[8]; short8 v; } pk;
#pragma unroll
  for (int j = 0; j < 8; ++j) pk.s[j] = src[(size_t)j * 3072];
  *reinterpret_cast<short8*>(VtG + ((size_t)hb * D_ + d) * T_ + t0) = pk.v;
}

// ---------------- causal GQA flash attention ----------------
#define KVBLK 64
#define KPAD 136   // elems; granule 17x16B (odd) -> conflict-free b128
#define VTPAD 72   // elems; granule 9x16B (odd)
#define PPAD 72    // elems; granule 9x16B (odd); row len 64 <= 72 (round-3 bug: was 40)

__global__ __launch_bounds__(256, 3) void attn_fwd(const uint16_t* __restrict__ Qb,
                                                   const uint16_t* __restrict__ Kb,
                                                   const uint16_t* __restrict__ VtG,
                                                   uint16_t* __restrict__ Ab) {
  __shared__ __align__(16) uint16_t Kl[KVBLK * KPAD];   // 17408 B
  __shared__ __align__(16) uint16_t Vtl[D_ * VTPAD];    // 18432 B
  __shared__ __align__(16) uint16_t Pl[4 * 16 * PPAD];  //  9216 B  (total 45056 -> 3 blk/CU)
  const int tid = threadIdx.x;
  const int w = tid >> 6, lane = tid & 63;
  const int lm = lane & 15, lg = lane >> 4;
  const int bh = blockIdx.y;
  const int b = bh >> 4, h = bh & 15;
  const int kvh = h >> 2;
  const int qt = (blockIdx.x + bh) & 31;  // load-balance swizzle
  const int q0 = qt * 64;

  const uint16_t* Qw = Qb + (((size_t)(b * H_ + h)) * T_ + q0 + w * 16) * D_;
  short8 qf[4];
#pragma unroll
  for (int kk = 0; kk < 4; ++kk)
    qf[kk] = *reinterpret_cast<const short8*>(Qw + (size_t)lm * D_ + kk * 32 + lg * 8);

  f32x4 o[8];
  const f32x4 z4 = {0.f, 0.f, 0.f, 0.f};
#pragma unroll
  for (int f = 0; f < 8; ++f) o[f] = z4;
  float mrow[4] = {-1e30f, -1e30f, -1e30f, -1e30f};
  float lrow[4] = {0.f, 0.f, 0.f, 0.f};

  const float sc = 0.08838834764831845f * 1.44269504088896341f;  // 1/sqrt(128) * log2e

  const uint16_t* Kbase = Kb + ((size_t)(b * KVH_ + kvh)) * T_ * D_;
  const uint16_t* Vtbase = VtG + ((size_t)(b * KVH_ + kvh)) * D_ * T_;
  uint16_t* Pw = Pl + w * 16 * PPAD;

  for (int t = 0; t <= qt; ++t) {
    const int kv0 = t * KVBLK;
    __syncthreads();  // prior tile's LDS reads done before restage
    // stage K [64][128] -> Kl[64][KPAD]
#pragma unroll
    for (int it = 0; it < 4; ++it) {
      const int flat = (it * 256 + tid) * 8;
      const int r = flat >> 7, c = flat & 127;
      short8 kvv = *reinterpret_cast<const short8*>(Kbase + ((size_t)(kv0 + r)) * D_ + c);
      *reinterpret_cast<short8*>(Kl + r * KPAD + c) = kvv;
    }
    // stage V^T [128][64] -> Vtl[128][VTPAD]
#pragma unroll
    for (int it = 0; it < 4; ++it) {
      const int flat = (it * 256 + tid) * 8;
      const int dd = flat >> 6, c = flat & 63;
      short8 vv = *reinterpret_cast<const short8*>(Vtbase + (size_t)dd * T_ + kv0 + c);
      *reinterpret_cast<short8*>(Vtl + dd * VTPAD + c) = vv;
    }
    __syncthreads();

    // S = Q K^T : 4 col-frags x 4 k-frags
    f32x4 s[4];
#pragma unroll
    for (int nf = 0; nf < 4; ++nf) s[nf] = z4;
#pragma unroll
    for (int nf = 0; nf < 4; ++nf)
#pragma unroll
      for (int kk = 0; kk < 4; ++kk) {
        short8 kf = *reinterpret_cast<const short8*>(Kl + (nf * 16 + lm) * KPAD + kk * 32 + lg * 8);
        s[nf] = __builtin_amdgcn_mfma_f32_16x16x32_bf16(qf[kk], kf, s[nf], 0, 0, 0);
      }

    const int rowg = q0 + w * 16 + lg * 4;
    const bool diag = (t == qt);
    float tmax[4] = {-1e30f, -1e30f, -1e30f, -1e30f};
#pragma unroll
    for (int nf = 0; nf < 4; ++nf) {
      const int colg = kv0 + nf * 16 + lm;
#pragma unroll
      for (int r = 0; r < 4; ++r) {
        float v = s[nf][r] * sc;
        if (diag && colg > rowg + r) v = -1e30f;
        s[nf][r] = v;
        tmax[r] = fmaxf(tmax[r], v);
      }
    }
#pragma unroll
    for (int r = 0; r < 4; ++r) {
      float v = tmax[r];
      v = fmaxf(v, __shfl_xor(v, 1));
      v = fmaxf(v, __shfl_xor(v, 2));
      v = fmaxf(v, __shfl_xor(v, 4));
      v = fmaxf(v, __shfl_xor(v, 8));
      tmax[r] = v;
    }
    // defer-max: skip rescale when tile max didn't grow past threshold
    bool grow = false;
#pragma unroll
    for (int r = 0; r < 4; ++r) grow = grow || (tmax[r] > mrow[r] + 8.f);
    if (__any((int)grow)) {
#pragma unroll
      for (int r = 0; r < 4; ++r) {
        const float nm = fmaxf(mrow[r], tmax[r]);
        const float al = exp2f(mrow[r] - nm);
        mrow[r] = nm;
        lrow[r] *= al;
#pragma unroll
        for (int f = 0; f < 8; ++f) o[f][r] *= al;
      }
    }
    float rsum[4] = {0.f, 0.f, 0.f, 0.f};
#pragma unroll
    for (int nf = 0; nf < 4; ++nf)
#pragma unroll
      for (int r = 0; r < 4; ++r) {
        const float p = exp2f(s[nf][r] - mrow[r]);
        rsum[r] += p;
        Pw[(lg * 4 + r) * PPAD + nf * 16 + lm] = f2bf(p);
      }
#pragma unroll
    for (int r = 0; r < 4; ++r) {
      float v = rsum[r];
      v += __shfl_xor(v, 1);
      v += __shfl_xor(v, 2);
      v += __shfl_xor(v, 4);
      v += __shfl_xor(v, 8);
      lrow[r] += v;
    }
    // P is wave-private: drain ds_writes, no cross-wave barrier needed
    asm volatile("s_waitcnt lgkmcnt(0)" ::: "memory");
    short8 pf[2];
#pragma unroll
    for (int ks = 0; ks < 2; ++ks)
      pf[ks] = *reinterpret_cast<const short8*>(Pw + lm * PPAD + ks * 32 + lg * 8);
#pragma unroll
    for (int f = 0; f < 8; ++f)
#pragma unroll
      for (int ks = 0; ks < 2; ++ks) {
        short8 vf = *reinterpret_cast<const short8*>(Vtl + (f * 16 + lm) * VTPAD + ks * 32 + lg * 8);
        o[f] = __builtin_amdgcn_mfma_f32_16x16x32_bf16(pf[ks], vf, o[f], 0, 0, 0);
      }
  }

#pragma unroll
  for (int f = 0; f < 8; ++f) {
    const int col = h * D_ + f * 16 + lm;
#pragma unroll
    for (int r = 0; r < 4; ++r) {
      const int trow = q0 + w * 16 + lg * 4 + r;
      const float v = o[f][r] / lrow[r];
      Ab[((size_t)(b * T_ + trow)) * (H_ * D_) + col] = f2bf(v);
    }
  }
}

// ---------------- launch ----------------
extern "C" void kernel_launch(void* const* d_in, const int* in_sizes, int n_in,
                              void* d_out, int out_size, void* d_ws, size_t ws_size,
                              hipStream_t stream) {
  const float* hidden = (const float*)d_in[0];
  const float* cosp   = (const float*)d_in[1];
  const float* sinp   = (const float*)d_in[2];
  // d_in[3] = attention_mask: exactly causal, implemented in-kernel
  const float* Wq = (const float*)d_in[4];
  const float* bq = (const float*)d_in[5];
  const float* Wk = (const float*)d_in[6];
  const float* bk = (const float*)d_in[7];
  const float* Wv = (const float*)d_in[8];
  const float* bv = (const float*)d_in[9];
  const float* Wo = (const float*)d_in[10];

  char* ws = (char*)d_ws;
  uint16_t* hidb   = (uint16_t*)(ws);              // 4096x2048 bf16   16,777,216 B
  uint16_t* wqkv   = (uint16_t*)(ws + 16777216);   // 3072x2048 bf16   12,582,912 B
  uint16_t* wob    = (uint16_t*)(ws + 29360128);   // 2048x2048 bf16    8,388,608 B
  float*    biasq  = (float*)   (ws + 37748736);   // 3072 f32             12,288 B
  uint16_t* qkvraw = (uint16_t*)(ws + 37761024);   // 4096x3072 bf16   25,165,824 B
  uint16_t* Qb     = (uint16_t*)(ws + 62926848);   // [2][16][2048][128] 16,777,216 B
  uint16_t* Kb     = (uint16_t*)(ws + 79704064);   // [2][4][2048][128]   4,194,304 B
  uint16_t* VtG    = (uint16_t*)(ws + 83898368);   // [2][4][128][2048]   4,194,304 B
  uint16_t* Ab     = (uint16_t*)(ws + 88092672);   // [2][2048][2048]   16,777,216 B

  cvt_f32_bf16<<<8192, 256, 0, stream>>>(hidden, hidb, 8388608);
  cvt_f32_bf16<<<4096, 256, 0, stream>>>(Wq, wqkv, 4194304);
  cvt_f32_bf16<<<1024, 256, 0, stream>>>(Wk, wqkv + 4194304, 1048576);
  cvt_f32_bf16<<<1024, 256, 0, stream>>>(Wv, wqkv + 5242880, 1048576);
  cvt_f32_bf16<<<4096, 256, 0, stream>>>(Wo, wob, 4194304);
  concat_bias<<<12, 256, 0, stream>>>(bq, bk, bv, biasq);

  // QKV projection: [4096,2048] x [3072,2048]^T -> [4096,3072] (+bias)
  gemm_bt<false, true><<<dim3(24, 32), 256, 0, stream>>>(hidb, wqkv, qkvraw, biasq, 4096, 3072, 2048);
  // RoPE + scatter Q,K
  rope_scatter<<<dim3(10, 4096), 256, 0, stream>>>(qkvraw, cosp, sinp, Qb, Kb);
  // V transpose to [d][t]
  transpose_v<<<dim3(128, 8), 256, 0, stream>>>(qkvraw, VtG);
  // causal GQA flash attention -> Ab [b][t][h*128+d] bf16
  attn_fwd<<<dim3(32, 32), 256, 0, stream>>>(Qb, Kb, VtG, Ab);
  // output projection: [4096,2048] x [2048,2048]^T -> d_out fp32
  gemm_bt<true, false><<<dim3(16, 32), 256, 0, stream>>>(Ab, wob, d_out, nullptr, 4096, 2048, 2048);
}